// Round 2
// baseline (66.293 us; speedup 1.0000x reference)
//
#include <hip/hip_runtime.h>
#include <hip/hip_bf16.h>
#include <math.h>

// Scalar LSTM recurrence, 8192 steps, output h_t each step.
// x (input bit) is the fed-back h, so z = h*(wi+wh) + b.
// Strictly serial -> run on one thread; detect the exact (bitwise) fixed
// point / period-2 cycle of the float32 map, then parallel-fill the tail.

__device__ __forceinline__ float fast_sigmoid(float x) {
    return 1.0f / (1.0f + __expf(-x));
}

__device__ __forceinline__ float fast_tanh(float x) {
    float e = __expf(-2.0f * x);
    return __fdividef(1.0f - e, 1.0f + e);
}

__global__ __launch_bounds__(256)
void lstm_scan_kernel(const float* __restrict__ Wi,
                      const float* __restrict__ Wh,
                      const float* __restrict__ b,
                      float* __restrict__ out,
                      int n) {
    __shared__ int   s_stop;
    __shared__ float s_fa, s_fb;

    if (threadIdx.x == 0) {
        const float w0 = Wi[0] + Wh[0];
        const float w1 = Wi[1] + Wh[1];
        const float w2 = Wi[2] + Wh[2];
        const float w3 = Wi[3] + Wh[3];
        const float b0 = b[0], b1 = b[1], b2 = b[2], b3 = b[3];

        float c = 0.0f, h = 0.0f;                 // S_{t-1}
        const float qnan = __int_as_float(0x7fc00000);
        float cp = qnan, hp = qnan;               // S_{t-2} (NaN: never matches)

        int   stop = n;                            // first index to be filled
        float fa = 0.0f, fb = 0.0f;                // fill pattern fa, fb, fa, fb, ...

        for (int t = 0; t < n; ++t) {
            // gate pre-activations: z = h*(wi+wh) + b  (order i, f, g, o)
            float zi = fmaf(h, w0, b0);
            float zf = fmaf(h, w1, b1);
            float zg = fmaf(h, w2, b2);
            float zo = fmaf(h, w3, b3);

            float ig = fast_sigmoid(zi);
            float fg = fast_sigmoid(zf);
            float gg = fast_tanh(zg);
            float og = fast_sigmoid(zo);

            float nc = fmaf(fg, c, ig * gg);       // S_t
            float nh = og * fast_tanh(nc);

            out[t] = nh;

            // exact fixed point: all subsequent states identical
            if (nc == c && nh == h) {
                stop = t + 1; fa = nh; fb = nh;
                break;
            }
            // exact period-2 cycle: outputs alternate h_{t-1}, h_t
            if (nc == cp && nh == hp) {
                stop = t + 1; fa = h; fb = nh;
                break;
            }

            cp = c;  hp = h;
            c  = nc; h  = nh;
        }

        s_stop = stop;
        s_fa   = fa;
        s_fb   = fb;
    }

    __syncthreads();

    const int   stop = s_stop;
    const float fa = s_fa, fb = s_fb;
    for (int k = stop + (int)threadIdx.x; k < n; k += (int)blockDim.x) {
        out[k] = ((k - stop) & 1) ? fb : fa;
    }
}

extern "C" void kernel_launch(void* const* d_in, const int* in_sizes, int n_in,
                              void* d_out, int out_size, void* d_ws, size_t ws_size,
                              hipStream_t stream) {
    const float* Wi = (const float*)d_in[0];
    const float* Wh = (const float*)d_in[1];
    const float* b  = (const float*)d_in[2];
    float* out = (float*)d_out;

    lstm_scan_kernel<<<1, 256, 0, stream>>>(Wi, Wh, b, out, out_size);
}

// Round 3
// 63.575 us; speedup vs baseline: 1.0428x; 1.0428x over previous
//
#include <hip/hip_runtime.h>
#include <hip/hip_bf16.h>
#include <math.h>

// Scalar LSTM recurrence, 8192 steps, output h_t each step.
// x (input bit) is the fed-back h, so z = h*(wi+wh) + b.
// Strictly serial -> one lane runs the recurrence; detect the exact
// (bitwise) period-1 / period-2 fixed point of the float32 map, then
// parallel-fill the tail with all 256 threads.
//
// This revision folds log2(e) into the precomputed weights so each
// activation is fma -> v_exp_f32 -> add -> v_rcp_f32 with no on-chain
// multiply (A/B test: is the serial phase a visible share of dur_us?).

__global__ __launch_bounds__(256)
void lstm_scan_kernel(const float* __restrict__ Wi,
                      const float* __restrict__ Wh,
                      const float* __restrict__ b,
                      float* __restrict__ out,
                      int n) {
    __shared__ int   s_stop;
    __shared__ float s_fa, s_fb;

    if (threadIdx.x == 0) {
        const float LOG2E = 1.4426950408889634f;

        // sigmoid gates (i, f, o): sig(z) = 1 / (1 + exp2(-(h*w+b)*log2e))
        //   u = fma(h, a_k, d_k) with a_k = -w_k*log2e, d_k = -b_k*log2e
        const float a0 = -(Wi[0] + Wh[0]) * LOG2E, d0 = -b[0] * LOG2E; // i
        const float a1 = -(Wi[1] + Wh[1]) * LOG2E, d1 = -b[1] * LOG2E; // f
        const float a3 = -(Wi[3] + Wh[3]) * LOG2E, d3 = -b[3] * LOG2E; // o
        // tanh gate (g): tanh(z) = (1-e)/(1+e), e = exp2(-2*z*log2e)
        const float a2 = -2.0f * (Wi[2] + Wh[2]) * LOG2E, d2 = -2.0f * b[2] * LOG2E;
        // tanh(new_c): e = exp2(new_c * M2)
        const float M2 = -2.0f * LOG2E;

        float c = 0.0f, h = 0.0f;                 // S_{t-1}
        const float qnan = __int_as_float(0x7fc00000);
        float cp = qnan, hp = qnan;               // S_{t-2} (NaN: never matches)

        int   stop = n;                            // first index to be filled
        float fa = 0.0f, fb = 0.0f;                // fill pattern fa, fb, ...

        for (int t = 0; t < n; ++t) {
            float ei = __builtin_amdgcn_exp2f(fmaf(h, a0, d0));
            float ef = __builtin_amdgcn_exp2f(fmaf(h, a1, d1));
            float eg = __builtin_amdgcn_exp2f(fmaf(h, a2, d2));
            float eo = __builtin_amdgcn_exp2f(fmaf(h, a3, d3));

            float ig = __builtin_amdgcn_rcpf(1.0f + ei);
            float fg = __builtin_amdgcn_rcpf(1.0f + ef);
            float gg = (1.0f - eg) * __builtin_amdgcn_rcpf(1.0f + eg);
            float og = __builtin_amdgcn_rcpf(1.0f + eo);

            float nc = fmaf(fg, c, ig * gg);       // S_t
            float ec = __builtin_amdgcn_exp2f(nc * M2);
            float nh = og * ((1.0f - ec) * __builtin_amdgcn_rcpf(1.0f + ec));

            out[t] = nh;

            // exact fixed point: all subsequent states identical
            if (nc == c && nh == h) {
                stop = t + 1; fa = nh; fb = nh;
                break;
            }
            // exact period-2 cycle: outputs alternate h_{t-1}, h_t
            if (nc == cp && nh == hp) {
                stop = t + 1; fa = h; fb = nh;
                break;
            }

            cp = c;  hp = h;
            c  = nc; h  = nh;
        }

        s_stop = stop;
        s_fa   = fa;
        s_fb   = fb;
    }

    __syncthreads();

    const int   stop = s_stop;
    const float fa = s_fa, fb = s_fb;
    for (int k = stop + (int)threadIdx.x; k < n; k += (int)blockDim.x) {
        out[k] = ((k - stop) & 1) ? fb : fa;
    }
}

extern "C" void kernel_launch(void* const* d_in, const int* in_sizes, int n_in,
                              void* d_out, int out_size, void* d_ws, size_t ws_size,
                              hipStream_t stream) {
    const float* Wi = (const float*)d_in[0];
    const float* Wh = (const float*)d_in[1];
    const float* b  = (const float*)d_in[2];
    float* out = (float*)d_out;

    lstm_scan_kernel<<<1, 256, 0, stream>>>(Wi, Wh, b, out, out_size);
}